// Round 13
// baseline (219.452 us; speedup 1.0000x reference)
//
#include <hip/hip_runtime.h>
#include <hip/hip_fp16.h>

typedef _Float16 f16;
typedef f16 f16x8 __attribute__((ext_vector_type(8)));
typedef float f32x4 __attribute__((ext_vector_type(4)));
typedef unsigned int u32x4 __attribute__((ext_vector_type(4)));

// ---------------- utility kernels ----------------

__global__ void k_zero_i32(int* __restrict__ p, int n) {
    int i = blockIdx.x * blockDim.x + threadIdx.x;
    if (i < n) p[i] = 0;
}

__global__ void k_count(const int* __restrict__ col, int E, int* __restrict__ cnt) {
    int e = blockIdx.x * blockDim.x + threadIdx.x;
    if (e < E) atomicAdd(&cnt[col[e]], 1);
}

// ---- 3-pass parallel exclusive scan over cnt[0..N) -> starts[0..N] ----
__global__ void k_bsum(const int* __restrict__ cnt, int N, int* __restrict__ bsum) {
    __shared__ int wt[4];
    int t = threadIdx.x;
    int i0 = blockIdx.x * 1024 + t * 4;
    int s = 0;
    #pragma unroll
    for (int j = 0; j < 4; ++j) { int i = i0 + j; if (i < N) s += cnt[i]; }
    #pragma unroll
    for (int off = 32; off > 0; off >>= 1) s += __shfl_down(s, off, 64);
    if ((t & 63) == 0) wt[t >> 6] = s;
    __syncthreads();
    if (t == 0) bsum[blockIdx.x] = wt[0] + wt[1] + wt[2] + wt[3];
}

__global__ void k_bscan(int* __restrict__ bsum, int nb, int* __restrict__ starts, int N) {
    int lane = threadIdx.x;
    int carry = 0;
    for (int base = 0; base < nb; base += 64) {
        int i = base + lane;
        int v = (i < nb) ? bsum[i] : 0;
        int s = v;
        #pragma unroll
        for (int off = 1; off < 64; off <<= 1) {
            int u = __shfl_up(s, off, 64);
            if (lane >= off) s += u;
        }
        if (i < nb) bsum[i] = carry + s - v;
        carry += __shfl(s, 63, 64);
    }
    if (lane == 0) starts[N] = carry;
}

// pass 3 (+fused dinv)
__global__ void k_scan_apply(const int* __restrict__ cnt, const int* __restrict__ bsum,
                             int* __restrict__ starts, float* __restrict__ dinv, int N) {
    __shared__ int wt[4];
    int t = threadIdx.x;
    int lane = t & 63;
    int w = t >> 6;
    int i0 = blockIdx.x * 1024 + t * 4;
    int v[4];
    int ts = 0;
    #pragma unroll
    for (int j = 0; j < 4; ++j) { int i = i0 + j; v[j] = (i < N) ? cnt[i] : 0; ts += v[j]; }
    int s = ts;
    #pragma unroll
    for (int off = 1; off < 64; off <<= 1) {
        int u = __shfl_up(s, off, 64);
        if (lane >= off) s += u;
    }
    if (lane == 63) wt[w] = s;
    __syncthreads();
    int woff = 0;
    if (w > 0) woff = wt[0];
    if (w > 1) woff += wt[1];
    if (w > 2) woff += wt[2];
    int base = bsum[blockIdx.x] + woff + (s - ts);
    int run = base;
    #pragma unroll
    for (int j = 0; j < 4; ++j) {
        int i = i0 + j;
        if (i < N) {
            starts[i] = run;
            dinv[i] = rsqrtf((float)v[j] + 1.0f);
        }
        run += v[j];
    }
}

// XCD-windowed CSR fill
__global__ void k_fill_xcd(const int* __restrict__ row, const int* __restrict__ col, int E,
                           const int* __restrict__ starts, int* __restrict__ cnt,
                           int* __restrict__ csr, int N) {
    const int w = blockIdx.x & 7;
    const int chunk = blockIdx.x >> 3;
    const int nchunks = gridDim.x >> 3;
    const int W = (N + 7) / 8;
    const int c0 = w * W;
    const int c1 = min(N, c0 + W);
    const int stride = nchunks * blockDim.x;
    for (int e = chunk * blockDim.x + threadIdx.x; e < E; e += stride) {
        int c = col[e];
        if (c >= c0 && c < c1) {
            int pos = starts[c] + atomicSub(&cnt[c], 1) - 1;
            csr[pos] = row[e];
        }
    }
}

// fused prep: x fp32->fp16 (range 0), weight transpose+cast (range 1),
// pooled zero (range 2). One launch instead of three.
__global__ void k_prep(const float* __restrict__ x, __half* __restrict__ X16, long nx4,
                       const float* __restrict__ W1, const float* __restrict__ W2,
                       const float* __restrict__ W3, f16* __restrict__ Wt1,
                       f16* __restrict__ Wt2, f16* __restrict__ Wt3,
                       float* __restrict__ pooled, int npool) {
    long idx = (long)blockIdx.x * blockDim.x + threadIdx.x;
    if (idx < nx4) {
        long i = idx * 4;
        float4 v = *(const float4*)&x[i];
        __half2 h0 = __floats2half2_rn(v.x, v.y);
        __half2 h1 = __floats2half2_rn(v.z, v.w);
        uint2 q; q.x = *(unsigned int*)&h0; q.y = *(unsigned int*)&h1;
        *(uint2*)&X16[i] = q;
        return;
    }
    long j = idx - nx4;
    if (j < 32768) {
        if (j < 8192) {                    // W1: 64x128 -> [128][72]
            int k = (int)(j >> 7), m = (int)(j & 127);
            Wt1[m * 72 + k] = (f16)W1[j];
        } else if (j < 24576) {            // W2: 128x128 -> [128][136]
            long u = j - 8192;
            int k = (int)(u >> 7), m = (int)(u & 127);
            Wt2[m * 136 + k] = (f16)W2[u];
        } else {                           // W3: 128x64 -> [64][136]
            long u = j - 24576;
            int k = (int)(u >> 6), m = (int)(u & 63);
            Wt3[m * 136 + k] = (f16)W3[u];
        }
        return;
    }
    long z = j - 32768;
    if (z < npool) pooled[z] = 0.0f;
}

// ---------------- MFMA fp16 GEMM ----------------

template<int K, int M, bool BIAS, bool RELU, typename OT>
__global__ __launch_bounds__(256) void k_gemm_mfma(const f16* __restrict__ A,
                                                   const f16* __restrict__ Wt,
                                                   const float* __restrict__ bias,
                                                   OT* __restrict__ P, int N) {
    constexpr int KP = K + 8;
    constexpr int KK = K / 32;
    __shared__ f16 Wl[M * KP];
    const int t = threadIdx.x;
    constexpr int CH = (M * KP * 2) / 16;
    {
        const uint4* src = (const uint4*)Wt;
        uint4* dst = (uint4*)Wl;
        for (int i = t; i < CH; i += 256) dst[i] = src[i];
    }
    __syncthreads();
    const int lane = t & 63;
    const int wave = t >> 6;
    const int r = lane & 15;
    const int q = lane >> 4;
    const int arow = blockIdx.x * 64 + wave * 16 + r;
    f16x8 a[KK];
    #pragma unroll
    for (int kk = 0; kk < KK; ++kk) {
        if (arow < N) a[kk] = *(const f16x8*)&A[(long)arow * K + kk * 32 + q * 8];
        else { f16x8 z = {0, 0, 0, 0, 0, 0, 0, 0}; a[kk] = z; }
    }
    const int drow0 = blockIdx.x * 64 + wave * 16 + q * 4;
    #pragma unroll
    for (int ct = 0; ct < M / 16; ++ct) {
        const int col = ct * 16 + r;
        f32x4 acc = {0.f, 0.f, 0.f, 0.f};
        #pragma unroll
        for (int kk = 0; kk < KK; ++kk) {
            f16x8 b = *(const f16x8*)&Wl[col * KP + kk * 32 + q * 8];
            acc = __builtin_amdgcn_mfma_f32_16x16x32_f16(a[kk], b, acc, 0, 0, 0);
        }
        float bb = BIAS ? bias[col] : 0.f;
        #pragma unroll
        for (int g = 0; g < 4; ++g) {
            int rr = drow0 + g;
            if (rr < N) {
                float v = acc[g] + bb;
                if (RELU) v = fmaxf(v, 0.f);
                if constexpr (__is_same(OT, f16)) P[(long)rr * M + col] = (f16)v;
                else P[(long)rr * M + col] = v;
            }
        }
    }
}

// ---------------- fp16-gather aggregation ----------------
// 4-wide neighbor unroll; csr reads + H stores NONTEMPORAL so the L2 keeps
// the P16 gather table (the only reused data) instead of streamed lines.

template<int M, bool BIAS, bool RELU, typename OT>
__global__ void k_agg16(const __half* __restrict__ P16, const int* __restrict__ starts,
                        const int* __restrict__ csr, const float* __restrict__ dinv,
                        const float* __restrict__ b, OT* __restrict__ H, int N) {
    constexpr int TPN = M / 8;
    constexpr int NPB = 256 / TPN;
    int local = threadIdx.x / TPN;
    int fq = threadIdx.x % TPN;
    int f0 = fq * 8;
    int c = blockIdx.x * NPB + local;
    if (c >= N) return;
    int s = starts[c], e = starts[c + 1];
    float acc[8] = {};
    int i = s;
    for (; i + 3 < e; i += 4) {
        int r0 = __builtin_nontemporal_load(csr + i);
        int r1 = __builtin_nontemporal_load(csr + i + 1);
        int r2 = __builtin_nontemporal_load(csr + i + 2);
        int r3 = __builtin_nontemporal_load(csr + i + 3);
        float d0 = dinv[r0], d1 = dinv[r1], d2 = dinv[r2], d3 = dinv[r3];
        uint4 u0 = *(const uint4*)&P16[(long)r0 * M + f0];
        uint4 u1 = *(const uint4*)&P16[(long)r1 * M + f0];
        uint4 u2 = *(const uint4*)&P16[(long)r2 * M + f0];
        uint4 u3 = *(const uint4*)&P16[(long)r3 * M + f0];
        const __half2* h0 = (const __half2*)&u0;
        const __half2* h1 = (const __half2*)&u1;
        const __half2* h2 = (const __half2*)&u2;
        const __half2* h3 = (const __half2*)&u3;
        #pragma unroll
        for (int j = 0; j < 4; ++j) {
            float2 v0 = __half22float2(h0[j]);
            float2 v1 = __half22float2(h1[j]);
            float2 v2 = __half22float2(h2[j]);
            float2 v3 = __half22float2(h3[j]);
            acc[2 * j]     += v0.x * d0 + v1.x * d1 + v2.x * d2 + v3.x * d3;
            acc[2 * j + 1] += v0.y * d0 + v1.y * d1 + v2.y * d2 + v3.y * d3;
        }
    }
    for (; i < e; ++i) {
        int r0 = __builtin_nontemporal_load(csr + i);
        float d0 = dinv[r0];
        uint4 u0 = *(const uint4*)&P16[(long)r0 * M + f0];
        const __half2* h0 = (const __half2*)&u0;
        #pragma unroll
        for (int j = 0; j < 4; ++j) {
            float2 v0 = __half22float2(h0[j]);
            acc[2 * j]     += v0.x * d0;
            acc[2 * j + 1] += v0.y * d0;
        }
    }
    float dc = dinv[c];
    float dc2 = dc * dc;
    uint4 us = *(const uint4*)&P16[(long)c * M + f0];
    const __half2* hs = (const __half2*)&us;
    float v[8];
    #pragma unroll
    for (int j = 0; j < 4; ++j) {
        float2 fs = __half22float2(hs[j]);
        v[2 * j]     = dc * acc[2 * j]     + dc2 * fs.x;
        v[2 * j + 1] = dc * acc[2 * j + 1] + dc2 * fs.y;
    }
    if (BIAS) {
        float4 bb0 = *(const float4*)&b[f0];
        float4 bb1 = *(const float4*)&b[f0 + 4];
        v[0] += bb0.x; v[1] += bb0.y; v[2] += bb0.z; v[3] += bb0.w;
        v[4] += bb1.x; v[5] += bb1.y; v[6] += bb1.z; v[7] += bb1.w;
    }
    if (RELU) {
        #pragma unroll
        for (int j = 0; j < 8; ++j) v[j] = fmaxf(v[j], 0.f);
    }
    if constexpr (__is_same(OT, __half)) {
        __half2 h0 = __floats2half2_rn(v[0], v[1]);
        __half2 h1 = __floats2half2_rn(v[2], v[3]);
        __half2 h2 = __floats2half2_rn(v[4], v[5]);
        __half2 h3 = __floats2half2_rn(v[6], v[7]);
        u32x4 qo;
        qo.x = *(unsigned int*)&h0; qo.y = *(unsigned int*)&h1;
        qo.z = *(unsigned int*)&h2; qo.w = *(unsigned int*)&h3;
        __builtin_nontemporal_store(qo, (u32x4*)&H[(long)c * M + f0]);
    } else {
        f32x4 o0 = {v[0], v[1], v[2], v[3]};
        f32x4 o1 = {v[4], v[5], v[6], v[7]};
        __builtin_nontemporal_store(o0, (f32x4*)&H[(long)c * M + f0]);
        __builtin_nontemporal_store(o1, (f32x4*)&H[(long)c * M + f0 + 4]);
    }
}

// ---------------- fp32 fallback kernels (unexpected shapes) ----------------

__global__ void k_gemm_naive(const float* __restrict__ X, const float* __restrict__ W,
                             float* __restrict__ P, int N, int K, int M) {
    long idx = (long)blockIdx.x * blockDim.x + threadIdx.x;
    long total = (long)N * M;
    if (idx >= total) return;
    int n = (int)(idx / M);
    int m = (int)(idx - (long)n * M);
    const float* xr = X + (long)n * K;
    float acc = 0.0f;
    for (int k = 0; k < K; ++k) acc += xr[k] * W[k * M + m];
    P[idx] = acc;
}

template<int M>
__global__ void k_aggregate4(const float* __restrict__ P, const int* __restrict__ starts,
                             const int* __restrict__ csr, const float* __restrict__ dinv,
                             const float* __restrict__ b, float* __restrict__ H,
                             int N, int do_relu) {
    constexpr int TPN = M / 4;
    constexpr int NPB = 256 / TPN;
    int local = threadIdx.x / TPN;
    int fq = threadIdx.x % TPN;
    int c = blockIdx.x * NPB + local;
    if (c >= N) return;
    int s = starts[c], e = starts[c + 1];
    float4 acc = make_float4(0.f, 0.f, 0.f, 0.f);
    for (int i = s; i < e; ++i) {
        int r = csr[i];
        float dr = dinv[r];
        float4 p = *(const float4*)&P[(long)r * M + fq * 4];
        acc.x += p.x * dr; acc.y += p.y * dr; acc.z += p.z * dr; acc.w += p.w * dr;
    }
    float dc = dinv[c];
    float dc2 = dc * dc;
    float4 ps = *(const float4*)&P[(long)c * M + fq * 4];
    float4 bb = *(const float4*)&b[fq * 4];
    float4 v;
    v.x = dc * acc.x + dc2 * ps.x + bb.x;
    v.y = dc * acc.y + dc2 * ps.y + bb.y;
    v.z = dc * acc.z + dc2 * ps.z + bb.z;
    v.w = dc * acc.w + dc2 * ps.w + bb.w;
    if (do_relu) {
        v.x = fmaxf(v.x, 0.f); v.y = fmaxf(v.y, 0.f);
        v.z = fmaxf(v.z, 0.f); v.w = fmaxf(v.w, 0.f);
    }
    *(float4*)&H[(long)c * M + fq * 4] = v;
}

// ---------------- pooling + classifier ----------------

__device__ __forceinline__ int lower_bound_i(const int* __restrict__ a, int n, int key) {
    int lo = 0, hi = n;
    while (lo < hi) { int mid = (lo + hi) >> 1; if (a[mid] < key) lo = mid + 1; else hi = mid; }
    return lo;
}

// node-parallel partial pooling
__global__ void k_pool_part(const float* __restrict__ H, const int* __restrict__ batch,
                            int N, float* __restrict__ pooled) {
    const int f = threadIdx.x & 63;
    const int ln = threadIdx.x >> 6;
    int n0 = blockIdx.x * 64 + ln * 16;
    int n1 = min(n0 + 16, N);
    float acc = 0.f;
    int cur = -1;
    for (int n = n0; n < n1; ++n) {
        int g = batch[n];
        if (g != cur) {
            if (cur >= 0) atomicAdd(&pooled[cur * 64 + f], acc);
            acc = 0.f;
            cur = g;
        }
        acc += H[(long)n * 64 + f];
    }
    if (cur >= 0) atomicAdd(&pooled[cur * 64 + f], acc);
}

__global__ void k_final2(const float* __restrict__ pooled, const int* __restrict__ batch,
                         int N, const float* __restrict__ Wl, const float* __restrict__ bl,
                         float* __restrict__ out, int C) {
    __shared__ float pl[64];
    int g = blockIdx.x;
    int f = threadIdx.x;
    int lo = lower_bound_i(batch, N, g);
    int hi = lower_bound_i(batch, N, g + 1);
    float inv = 1.0f / fmaxf((float)(hi - lo), 1.0f);
    pl[f] = pooled[g * 64 + f] * inv;
    __syncthreads();
    if (f < C) {
        float o = bl[f];
        #pragma unroll 8
        for (int k = 0; k < 64; ++k) o += pl[k] * Wl[k * C + f];
        out[g * C + f] = o;
    }
}

__global__ void k_pool(const float* __restrict__ H, const int* __restrict__ batch,
                       int N, int M, float* __restrict__ pooled) {
    int g = blockIdx.x;
    int f = threadIdx.x;
    int lo = lower_bound_i(batch, N, g);
    int hi = lower_bound_i(batch, N, g + 1);
    float acc = 0.0f;
    for (int n = lo; n < hi; ++n) acc += H[(long)n * M + f];
    float inv = 1.0f / fmaxf((float)(hi - lo), 1.0f);
    pooled[(long)g * M + f] = acc * inv;
}

__global__ void k_final(const float* __restrict__ pooled, const float* __restrict__ Wl,
                        const float* __restrict__ bl, float* __restrict__ out,
                        int Gn, int F, int C) {
    int idx = blockIdx.x * blockDim.x + threadIdx.x;
    if (idx >= Gn * C) return;
    int g = idx / C;
    int j = idx - g * C;
    float acc = bl[j];
    for (int f = 0; f < F; ++f) acc += pooled[g * F + f] * Wl[f * C + j];
    out[idx] = acc;
}

// ---------------- launch ----------------

extern "C" void kernel_launch(void* const* d_in, const int* in_sizes, int n_in,
                              void* d_out, int out_size, void* d_ws, size_t ws_size,
                              hipStream_t stream) {
    const float* x  = (const float*)d_in[0];
    const int*   ei = (const int*)d_in[1];
    const int*   batch = (const int*)d_in[2];
    const float* W1 = (const float*)d_in[3];
    const float* b1 = (const float*)d_in[4];
    const float* W2 = (const float*)d_in[5];
    const float* b2 = (const float*)d_in[6];
    const float* W3 = (const float*)d_in[7];
    const float* b3 = (const float*)d_in[8];
    const float* Wl = (const float*)d_in[9];
    const float* bl = (const float*)d_in[10];

    const int N  = in_sizes[2];          // 50000
    const int E  = in_sizes[1] / 2;      // 800000
    const int C  = in_sizes[10];         // 10
    const int Gn = out_size / C;         // 512
    const int F1 = in_sizes[4];          // 128
    const int F2 = in_sizes[6];          // 128
    const int F3 = in_sizes[8];          // 64
    const int K0 = in_sizes[0] / N;      // 64

    const int* row = ei;
    const int* col = ei + E;

    // workspace layout (64B-aligned chunks)
    char* base = (char*)d_ws;
    size_t off = 0;
    auto alloc = [&](size_t bytes) {
        off = (off + 63) & ~(size_t)63;
        void* p = base + off;
        off += bytes;
        return p;
    };
    int* cnt     = (int*)alloc((size_t)N * 4);
    int* starts  = (int*)alloc((size_t)(N + 1) * 4);
    int* bsum    = (int*)alloc(256 * 4);
    int* csr     = (int*)alloc((size_t)E * 4);
    float* dinv  = (float*)alloc((size_t)N * 4);
    __half* X16  = (__half*)alloc((size_t)N * 64 * 2);
    __half* AX16 = (__half*)alloc((size_t)N * 64 * 2);
    __half* H1   = (__half*)alloc((size_t)N * 128 * 2);
    __half* P16a = (__half*)alloc((size_t)N * 128 * 2);
    __half* B16  = (__half*)alloc((size_t)N * 128 * 2);
    __half* P16b = (__half*)alloc((size_t)N * 64 * 2);
    float* H3    = (float*)alloc((size_t)N * 64 * 4);
    f16* Wt1     = (f16*)alloc((size_t)128 * 72 * 2);
    f16* Wt2     = (f16*)alloc((size_t)128 * 136 * 2);
    f16* Wt3     = (f16*)alloc((size_t)64 * 136 * 2);
    float* pooled = (float*)alloc((size_t)Gn * 64 * 4);
    float* Afb   = (float*)alloc((size_t)N * 128 * 4);
    float* Bfb   = (float*)alloc((size_t)N * 128 * 4);

    const int BLK = 256;
    auto blocks = [](long n, int b) { return (int)((n + b - 1) / b); };
    const int nb = blocks(N, 1024);

    // --- build CSR (+ dinv fused into scan_apply) ---
    k_zero_i32<<<blocks(N, BLK), BLK, 0, stream>>>(cnt, N);
    k_count<<<blocks(E, BLK), BLK, 0, stream>>>(col, E, cnt);
    k_bsum<<<nb, 256, 0, stream>>>(cnt, N, bsum);
    k_bscan<<<1, 64, 0, stream>>>(bsum, nb, starts, N);
    k_scan_apply<<<nb, 256, 0, stream>>>(cnt, bsum, starts, dinv, N);
    k_fill_xcd<<<128 * 8, 256, 0, stream>>>(row, col, E, starts, cnt, csr, N);

    const bool fast = (K0 == 64 && F1 == 128 && F2 == 128 && F3 == 64);

    if (fast) {
        // fused prep: f2h + weight transpose + pooled zero
        long nx4 = (long)N * 64 / 4;
        long prep_threads = nx4 + 32768 + (long)Gn * 64;
        k_prep<<<blocks(prep_threads, BLK), BLK, 0, stream>>>(
            x, X16, nx4, W1, W2, W3, Wt1, Wt2, Wt3, pooled, Gn * 64);

        // layer 1 (reordered): H1 = relu( (A_hat X) W1 + b1 )
        k_agg16<64, false, false, __half><<<blocks(N, 32), 256, 0, stream>>>(X16, starts, csr, dinv, nullptr, AX16, N);
        k_gemm_mfma<64, 128, true, true, f16><<<blocks(N, 64), 256, 0, stream>>>((const f16*)AX16, Wt1, b1, (f16*)H1, N);
        // layer 2: B16 = relu( A_hat (H1 W2) + b2 )
        k_gemm_mfma<128, 128, false, false, f16><<<blocks(N, 64), 256, 0, stream>>>((const f16*)H1, Wt2, nullptr, (f16*)P16a, N);
        k_agg16<128, true, true, __half><<<blocks(N, 16), 256, 0, stream>>>(P16a, starts, csr, dinv, b2, B16, N);
        // layer 3: H3 = A_hat (B16 W3) + b3
        k_gemm_mfma<128, 64, false, false, f16><<<blocks(N, 64), 256, 0, stream>>>((const f16*)B16, Wt3, nullptr, (f16*)P16b, N);
        k_agg16<64, true, false, float><<<blocks(N, 32), 256, 0, stream>>>(P16b, starts, csr, dinv, b3, H3, N);
        // node-parallel pool + per-graph classifier
        k_pool_part<<<blocks(N, 64), 256, 0, stream>>>(H3, batch, N, pooled);
        k_final2<<<Gn, 64, 0, stream>>>(pooled, batch, N, Wl, bl, (float*)d_out, C);
    } else {
        k_gemm_naive<<<blocks((long)N * F1, BLK), BLK, 0, stream>>>(x, W1, Afb, N, K0, F1);
        k_aggregate4<128><<<blocks(N, 8), 256, 0, stream>>>(Afb, starts, csr, dinv, b1, Bfb, N, 1);
        k_gemm_naive<<<blocks((long)N * F2, BLK), BLK, 0, stream>>>(Bfb, W2, Afb, N, F1, F2);
        k_aggregate4<128><<<blocks(N, 8), 256, 0, stream>>>(Afb, starts, csr, dinv, b2, Bfb, N, 1);
        k_gemm_naive<<<blocks((long)N * F3, BLK), BLK, 0, stream>>>(Bfb, W3, Afb, N, F2, F3);
        k_aggregate4<64><<<blocks(N, 16), 256, 0, stream>>>(Afb, starts, csr, dinv, b3, Bfb, N, 0);
        k_pool<<<Gn, F3, 0, stream>>>(Bfb, batch, N, F3, pooled);
        k_final<<<blocks(Gn * C, BLK), BLK, 0, stream>>>(pooled, Wl, bl, (float*)d_out, Gn, F3, C);
    }
}

// Round 14
// 204.155 us; speedup vs baseline: 1.0749x; 1.0749x over previous
//
#include <hip/hip_runtime.h>
#include <hip/hip_fp16.h>

typedef _Float16 f16;
typedef f16 f16x8 __attribute__((ext_vector_type(8)));
typedef float f32x4 __attribute__((ext_vector_type(4)));

// ---------------- utility kernels ----------------

__global__ void k_zero_i32(int* __restrict__ p, int n) {
    int i = blockIdx.x * blockDim.x + threadIdx.x;
    if (i < n) p[i] = 0;
}

__global__ void k_count(const int* __restrict__ col, int E, int* __restrict__ cnt) {
    int e = blockIdx.x * blockDim.x + threadIdx.x;
    if (e < E) atomicAdd(&cnt[col[e]], 1);
}

// ---- 3-pass parallel exclusive scan over cnt[0..N) -> starts[0..N] ----
__global__ void k_bsum(const int* __restrict__ cnt, int N, int* __restrict__ bsum) {
    __shared__ int wt[4];
    int t = threadIdx.x;
    int i0 = blockIdx.x * 1024 + t * 4;
    int s = 0;
    #pragma unroll
    for (int j = 0; j < 4; ++j) { int i = i0 + j; if (i < N) s += cnt[i]; }
    #pragma unroll
    for (int off = 32; off > 0; off >>= 1) s += __shfl_down(s, off, 64);
    if ((t & 63) == 0) wt[t >> 6] = s;
    __syncthreads();
    if (t == 0) bsum[blockIdx.x] = wt[0] + wt[1] + wt[2] + wt[3];
}

__global__ void k_bscan(int* __restrict__ bsum, int nb, int* __restrict__ starts, int N) {
    int lane = threadIdx.x;
    int carry = 0;
    for (int base = 0; base < nb; base += 64) {
        int i = base + lane;
        int v = (i < nb) ? bsum[i] : 0;
        int s = v;
        #pragma unroll
        for (int off = 1; off < 64; off <<= 1) {
            int u = __shfl_up(s, off, 64);
            if (lane >= off) s += u;
        }
        if (i < nb) bsum[i] = carry + s - v;
        carry += __shfl(s, 63, 64);
    }
    if (lane == 0) starts[N] = carry;
}

// pass 3 (+fused dinv)
__global__ void k_scan_apply(const int* __restrict__ cnt, const int* __restrict__ bsum,
                             int* __restrict__ starts, float* __restrict__ dinv, int N) {
    __shared__ int wt[4];
    int t = threadIdx.x;
    int lane = t & 63;
    int w = t >> 6;
    int i0 = blockIdx.x * 1024 + t * 4;
    int v[4];
    int ts = 0;
    #pragma unroll
    for (int j = 0; j < 4; ++j) { int i = i0 + j; v[j] = (i < N) ? cnt[i] : 0; ts += v[j]; }
    int s = ts;
    #pragma unroll
    for (int off = 1; off < 64; off <<= 1) {
        int u = __shfl_up(s, off, 64);
        if (lane >= off) s += u;
    }
    if (lane == 63) wt[w] = s;
    __syncthreads();
    int woff = 0;
    if (w > 0) woff = wt[0];
    if (w > 1) woff += wt[1];
    if (w > 2) woff += wt[2];
    int base = bsum[blockIdx.x] + woff + (s - ts);
    int run = base;
    #pragma unroll
    for (int j = 0; j < 4; ++j) {
        int i = i0 + j;
        if (i < N) {
            starts[i] = run;
            dinv[i] = rsqrtf((float)v[j] + 1.0f);
        }
        run += v[j];
    }
}

// XCD-windowed CSR fill
__global__ void k_fill_xcd(const int* __restrict__ row, const int* __restrict__ col, int E,
                           const int* __restrict__ starts, int* __restrict__ cnt,
                           int* __restrict__ csr, int N) {
    const int w = blockIdx.x & 7;
    const int chunk = blockIdx.x >> 3;
    const int nchunks = gridDim.x >> 3;
    const int W = (N + 7) / 8;
    const int c0 = w * W;
    const int c1 = min(N, c0 + W);
    const int stride = nchunks * blockDim.x;
    for (int e = chunk * blockDim.x + threadIdx.x; e < E; e += stride) {
        int c = col[e];
        if (c >= c0 && c < c1) {
            int pos = starts[c] + atomicSub(&cnt[c], 1) - 1;
            csr[pos] = row[e];
        }
    }
}

// fused prep: x fp32->fp16 (range 0), weight transpose+cast (range 1),
// pooled zero (range 2). One launch instead of three.
__global__ void k_prep(const float* __restrict__ x, __half* __restrict__ X16, long nx4,
                       const float* __restrict__ W1, const float* __restrict__ W2,
                       const float* __restrict__ W3, f16* __restrict__ Wt1,
                       f16* __restrict__ Wt2, f16* __restrict__ Wt3,
                       float* __restrict__ pooled, int npool) {
    long idx = (long)blockIdx.x * blockDim.x + threadIdx.x;
    if (idx < nx4) {
        long i = idx * 4;
        float4 v = *(const float4*)&x[i];
        __half2 h0 = __floats2half2_rn(v.x, v.y);
        __half2 h1 = __floats2half2_rn(v.z, v.w);
        uint2 q; q.x = *(unsigned int*)&h0; q.y = *(unsigned int*)&h1;
        *(uint2*)&X16[i] = q;
        return;
    }
    long j = idx - nx4;
    if (j < 32768) {
        if (j < 8192) {                    // W1: 64x128 -> [128][72]
            int k = (int)(j >> 7), m = (int)(j & 127);
            Wt1[m * 72 + k] = (f16)W1[j];
        } else if (j < 24576) {            // W2: 128x128 -> [128][136]
            long u = j - 8192;
            int k = (int)(u >> 7), m = (int)(u & 127);
            Wt2[m * 136 + k] = (f16)W2[u];
        } else {                           // W3: 128x64 -> [64][136]
            long u = j - 24576;
            int k = (int)(u >> 6), m = (int)(u & 63);
            Wt3[m * 136 + k] = (f16)W3[u];
        }
        return;
    }
    long z = j - 32768;
    if (z < npool) pooled[z] = 0.0f;
}

// ---------------- MFMA fp16 GEMM ----------------

template<int K, int M, bool BIAS, bool RELU, typename OT>
__global__ __launch_bounds__(256) void k_gemm_mfma(const f16* __restrict__ A,
                                                   const f16* __restrict__ Wt,
                                                   const float* __restrict__ bias,
                                                   OT* __restrict__ P, int N) {
    constexpr int KP = K + 8;
    constexpr int KK = K / 32;
    __shared__ f16 Wl[M * KP];
    const int t = threadIdx.x;
    constexpr int CH = (M * KP * 2) / 16;
    {
        const uint4* src = (const uint4*)Wt;
        uint4* dst = (uint4*)Wl;
        for (int i = t; i < CH; i += 256) dst[i] = src[i];
    }
    __syncthreads();
    const int lane = t & 63;
    const int wave = t >> 6;
    const int r = lane & 15;
    const int q = lane >> 4;
    const int arow = blockIdx.x * 64 + wave * 16 + r;
    f16x8 a[KK];
    #pragma unroll
    for (int kk = 0; kk < KK; ++kk) {
        if (arow < N) a[kk] = *(const f16x8*)&A[(long)arow * K + kk * 32 + q * 8];
        else { f16x8 z = {0, 0, 0, 0, 0, 0, 0, 0}; a[kk] = z; }
    }
    const int drow0 = blockIdx.x * 64 + wave * 16 + q * 4;
    #pragma unroll
    for (int ct = 0; ct < M / 16; ++ct) {
        const int col = ct * 16 + r;
        f32x4 acc = {0.f, 0.f, 0.f, 0.f};
        #pragma unroll
        for (int kk = 0; kk < KK; ++kk) {
            f16x8 b = *(const f16x8*)&Wl[col * KP + kk * 32 + q * 8];
            acc = __builtin_amdgcn_mfma_f32_16x16x32_f16(a[kk], b, acc, 0, 0, 0);
        }
        float bb = BIAS ? bias[col] : 0.f;
        #pragma unroll
        for (int g = 0; g < 4; ++g) {
            int rr = drow0 + g;
            if (rr < N) {
                float v = acc[g] + bb;
                if (RELU) v = fmaxf(v, 0.f);
                if constexpr (__is_same(OT, f16)) P[(long)rr * M + col] = (f16)v;
                else P[(long)rr * M + col] = v;
            }
        }
    }
}

// ---------------- fp16-gather aggregation, 4-wide neighbor unroll (R10) ----

template<int M, bool BIAS, bool RELU, typename OT>
__global__ void k_agg16(const __half* __restrict__ P16, const int* __restrict__ starts,
                        const int* __restrict__ csr, const float* __restrict__ dinv,
                        const float* __restrict__ b, OT* __restrict__ H, int N) {
    constexpr int TPN = M / 8;
    constexpr int NPB = 256 / TPN;
    int local = threadIdx.x / TPN;
    int fq = threadIdx.x % TPN;
    int f0 = fq * 8;
    int c = blockIdx.x * NPB + local;
    if (c >= N) return;
    int s = starts[c], e = starts[c + 1];
    float acc[8] = {};
    int i = s;
    for (; i + 3 < e; i += 4) {
        int r0 = csr[i], r1 = csr[i + 1], r2 = csr[i + 2], r3 = csr[i + 3];
        float d0 = dinv[r0], d1 = dinv[r1], d2 = dinv[r2], d3 = dinv[r3];
        uint4 u0 = *(const uint4*)&P16[(long)r0 * M + f0];
        uint4 u1 = *(const uint4*)&P16[(long)r1 * M + f0];
        uint4 u2 = *(const uint4*)&P16[(long)r2 * M + f0];
        uint4 u3 = *(const uint4*)&P16[(long)r3 * M + f0];
        const __half2* h0 = (const __half2*)&u0;
        const __half2* h1 = (const __half2*)&u1;
        const __half2* h2 = (const __half2*)&u2;
        const __half2* h3 = (const __half2*)&u3;
        #pragma unroll
        for (int j = 0; j < 4; ++j) {
            float2 v0 = __half22float2(h0[j]);
            float2 v1 = __half22float2(h1[j]);
            float2 v2 = __half22float2(h2[j]);
            float2 v3 = __half22float2(h3[j]);
            acc[2 * j]     += v0.x * d0 + v1.x * d1 + v2.x * d2 + v3.x * d3;
            acc[2 * j + 1] += v0.y * d0 + v1.y * d1 + v2.y * d2 + v3.y * d3;
        }
    }
    for (; i < e; ++i) {
        int r0 = csr[i];
        float d0 = dinv[r0];
        uint4 u0 = *(const uint4*)&P16[(long)r0 * M + f0];
        const __half2* h0 = (const __half2*)&u0;
        #pragma unroll
        for (int j = 0; j < 4; ++j) {
            float2 v0 = __half22float2(h0[j]);
            acc[2 * j]     += v0.x * d0;
            acc[2 * j + 1] += v0.y * d0;
        }
    }
    float dc = dinv[c];
    float dc2 = dc * dc;
    uint4 us = *(const uint4*)&P16[(long)c * M + f0];
    const __half2* hs = (const __half2*)&us;
    float v[8];
    #pragma unroll
    for (int j = 0; j < 4; ++j) {
        float2 fs = __half22float2(hs[j]);
        v[2 * j]     = dc * acc[2 * j]     + dc2 * fs.x;
        v[2 * j + 1] = dc * acc[2 * j + 1] + dc2 * fs.y;
    }
    if (BIAS) {
        float4 bb0 = *(const float4*)&b[f0];
        float4 bb1 = *(const float4*)&b[f0 + 4];
        v[0] += bb0.x; v[1] += bb0.y; v[2] += bb0.z; v[3] += bb0.w;
        v[4] += bb1.x; v[5] += bb1.y; v[6] += bb1.z; v[7] += bb1.w;
    }
    if (RELU) {
        #pragma unroll
        for (int j = 0; j < 8; ++j) v[j] = fmaxf(v[j], 0.f);
    }
    if constexpr (__is_same(OT, __half)) {
        __half2 h0 = __floats2half2_rn(v[0], v[1]);
        __half2 h1 = __floats2half2_rn(v[2], v[3]);
        __half2 h2 = __floats2half2_rn(v[4], v[5]);
        __half2 h3 = __floats2half2_rn(v[6], v[7]);
        uint4 qo;
        qo.x = *(unsigned int*)&h0; qo.y = *(unsigned int*)&h1;
        qo.z = *(unsigned int*)&h2; qo.w = *(unsigned int*)&h3;
        *(uint4*)&H[(long)c * M + f0] = qo;
    } else {
        *(float4*)&H[(long)c * M + f0]     = make_float4(v[0], v[1], v[2], v[3]);
        *(float4*)&H[(long)c * M + f0 + 4] = make_float4(v[4], v[5], v[6], v[7]);
    }
}

// ---------------- fp32 fallback kernels (unexpected shapes) ----------------

__global__ void k_gemm_naive(const float* __restrict__ X, const float* __restrict__ W,
                             float* __restrict__ P, int N, int K, int M) {
    long idx = (long)blockIdx.x * blockDim.x + threadIdx.x;
    long total = (long)N * M;
    if (idx >= total) return;
    int n = (int)(idx / M);
    int m = (int)(idx - (long)n * M);
    const float* xr = X + (long)n * K;
    float acc = 0.0f;
    for (int k = 0; k < K; ++k) acc += xr[k] * W[k * M + m];
    P[idx] = acc;
}

template<int M>
__global__ void k_aggregate4(const float* __restrict__ P, const int* __restrict__ starts,
                             const int* __restrict__ csr, const float* __restrict__ dinv,
                             const float* __restrict__ b, float* __restrict__ H,
                             int N, int do_relu) {
    constexpr int TPN = M / 4;
    constexpr int NPB = 256 / TPN;
    int local = threadIdx.x / TPN;
    int fq = threadIdx.x % TPN;
    int c = blockIdx.x * NPB + local;
    if (c >= N) return;
    int s = starts[c], e = starts[c + 1];
    float4 acc = make_float4(0.f, 0.f, 0.f, 0.f);
    for (int i = s; i < e; ++i) {
        int r = csr[i];
        float dr = dinv[r];
        float4 p = *(const float4*)&P[(long)r * M + fq * 4];
        acc.x += p.x * dr; acc.y += p.y * dr; acc.z += p.z * dr; acc.w += p.w * dr;
    }
    float dc = dinv[c];
    float dc2 = dc * dc;
    float4 ps = *(const float4*)&P[(long)c * M + fq * 4];
    float4 bb = *(const float4*)&b[fq * 4];
    float4 v;
    v.x = dc * acc.x + dc2 * ps.x + bb.x;
    v.y = dc * acc.y + dc2 * ps.y + bb.y;
    v.z = dc * acc.z + dc2 * ps.z + bb.z;
    v.w = dc * acc.w + dc2 * ps.w + bb.w;
    if (do_relu) {
        v.x = fmaxf(v.x, 0.f); v.y = fmaxf(v.y, 0.f);
        v.z = fmaxf(v.z, 0.f); v.w = fmaxf(v.w, 0.f);
    }
    *(float4*)&H[(long)c * M + fq * 4] = v;
}

// ---------------- pooling + classifier ----------------

__device__ __forceinline__ int lower_bound_i(const int* __restrict__ a, int n, int key) {
    int lo = 0, hi = n;
    while (lo < hi) { int mid = (lo + hi) >> 1; if (a[mid] < key) lo = mid + 1; else hi = mid; }
    return lo;
}

// node-parallel partial pooling
__global__ void k_pool_part(const float* __restrict__ H, const int* __restrict__ batch,
                            int N, float* __restrict__ pooled) {
    const int f = threadIdx.x & 63;
    const int ln = threadIdx.x >> 6;
    int n0 = blockIdx.x * 64 + ln * 16;
    int n1 = min(n0 + 16, N);
    float acc = 0.f;
    int cur = -1;
    for (int n = n0; n < n1; ++n) {
        int g = batch[n];
        if (g != cur) {
            if (cur >= 0) atomicAdd(&pooled[cur * 64 + f], acc);
            acc = 0.f;
            cur = g;
        }
        acc += H[(long)n * 64 + f];
    }
    if (cur >= 0) atomicAdd(&pooled[cur * 64 + f], acc);
}

__global__ void k_final2(const float* __restrict__ pooled, const int* __restrict__ batch,
                         int N, const float* __restrict__ Wl, const float* __restrict__ bl,
                         float* __restrict__ out, int C) {
    __shared__ float pl[64];
    int g = blockIdx.x;
    int f = threadIdx.x;
    int lo = lower_bound_i(batch, N, g);
    int hi = lower_bound_i(batch, N, g + 1);
    float inv = 1.0f / fmaxf((float)(hi - lo), 1.0f);
    pl[f] = pooled[g * 64 + f] * inv;
    __syncthreads();
    if (f < C) {
        float o = bl[f];
        #pragma unroll 8
        for (int k = 0; k < 64; ++k) o += pl[k] * Wl[k * C + f];
        out[g * C + f] = o;
    }
}

__global__ void k_pool(const float* __restrict__ H, const int* __restrict__ batch,
                       int N, int M, float* __restrict__ pooled) {
    int g = blockIdx.x;
    int f = threadIdx.x;
    int lo = lower_bound_i(batch, N, g);
    int hi = lower_bound_i(batch, N, g + 1);
    float acc = 0.0f;
    for (int n = lo; n < hi; ++n) acc += H[(long)n * M + f];
    float inv = 1.0f / fmaxf((float)(hi - lo), 1.0f);
    pooled[(long)g * M + f] = acc * inv;
}

__global__ void k_final(const float* __restrict__ pooled, const float* __restrict__ Wl,
                        const float* __restrict__ bl, float* __restrict__ out,
                        int Gn, int F, int C) {
    int idx = blockIdx.x * blockDim.x + threadIdx.x;
    if (idx >= Gn * C) return;
    int g = idx / C;
    int j = idx - g * C;
    float acc = bl[j];
    for (int f = 0; f < F; ++f) acc += pooled[g * F + f] * Wl[f * C + j];
    out[idx] = acc;
}

// ---------------- launch ----------------

extern "C" void kernel_launch(void* const* d_in, const int* in_sizes, int n_in,
                              void* d_out, int out_size, void* d_ws, size_t ws_size,
                              hipStream_t stream) {
    const float* x  = (const float*)d_in[0];
    const int*   ei = (const int*)d_in[1];
    const int*   batch = (const int*)d_in[2];
    const float* W1 = (const float*)d_in[3];
    const float* b1 = (const float*)d_in[4];
    const float* W2 = (const float*)d_in[5];
    const float* b2 = (const float*)d_in[6];
    const float* W3 = (const float*)d_in[7];
    const float* b3 = (const float*)d_in[8];
    const float* Wl = (const float*)d_in[9];
    const float* bl = (const float*)d_in[10];

    const int N  = in_sizes[2];          // 50000
    const int E  = in_sizes[1] / 2;      // 800000
    const int C  = in_sizes[10];         // 10
    const int Gn = out_size / C;         // 512
    const int F1 = in_sizes[4];          // 128
    const int F2 = in_sizes[6];          // 128
    const int F3 = in_sizes[8];          // 64
    const int K0 = in_sizes[0] / N;      // 64

    const int* row = ei;
    const int* col = ei + E;

    // workspace layout (64B-aligned chunks)
    char* base = (char*)d_ws;
    size_t off = 0;
    auto alloc = [&](size_t bytes) {
        off = (off + 63) & ~(size_t)63;
        void* p = base + off;
        off += bytes;
        return p;
    };
    int* cnt     = (int*)alloc((size_t)N * 4);
    int* starts  = (int*)alloc((size_t)(N + 1) * 4);
    int* bsum    = (int*)alloc(256 * 4);
    int* csr     = (int*)alloc((size_t)E * 4);
    float* dinv  = (float*)alloc((size_t)N * 4);
    __half* X16  = (__half*)alloc((size_t)N * 64 * 2);
    __half* AX16 = (__half*)alloc((size_t)N * 64 * 2);
    __half* H1   = (__half*)alloc((size_t)N * 128 * 2);
    __half* P16a = (__half*)alloc((size_t)N * 128 * 2);
    __half* B16  = (__half*)alloc((size_t)N * 128 * 2);
    __half* P16b = (__half*)alloc((size_t)N * 64 * 2);
    float* H3    = (float*)alloc((size_t)N * 64 * 4);
    f16* Wt1     = (f16*)alloc((size_t)128 * 72 * 2);
    f16* Wt2     = (f16*)alloc((size_t)128 * 136 * 2);
    f16* Wt3     = (f16*)alloc((size_t)64 * 136 * 2);
    float* pooled = (float*)alloc((size_t)Gn * 64 * 4);
    float* Afb   = (float*)alloc((size_t)N * 128 * 4);
    float* Bfb   = (float*)alloc((size_t)N * 128 * 4);

    const int BLK = 256;
    auto blocks = [](long n, int b) { return (int)((n + b - 1) / b); };
    const int nb = blocks(N, 1024);

    // --- build CSR (+ dinv fused into scan_apply) ---
    k_zero_i32<<<blocks(N, BLK), BLK, 0, stream>>>(cnt, N);
    k_count<<<blocks(E, BLK), BLK, 0, stream>>>(col, E, cnt);
    k_bsum<<<nb, 256, 0, stream>>>(cnt, N, bsum);
    k_bscan<<<1, 64, 0, stream>>>(bsum, nb, starts, N);
    k_scan_apply<<<nb, 256, 0, stream>>>(cnt, bsum, starts, dinv, N);
    k_fill_xcd<<<128 * 8, 256, 0, stream>>>(row, col, E, starts, cnt, csr, N);

    const bool fast = (K0 == 64 && F1 == 128 && F2 == 128 && F3 == 64);

    if (fast) {
        // fused prep: f2h + weight transpose + pooled zero
        long nx4 = (long)N * 64 / 4;
        long prep_threads = nx4 + 32768 + (long)Gn * 64;
        k_prep<<<blocks(prep_threads, BLK), BLK, 0, stream>>>(
            x, X16, nx4, W1, W2, W3, Wt1, Wt2, Wt3, pooled, Gn * 64);

        // layer 1 (reordered): H1 = relu( (A_hat X) W1 + b1 )
        k_agg16<64, false, false, __half><<<blocks(N, 32), 256, 0, stream>>>(X16, starts, csr, dinv, nullptr, AX16, N);
        k_gemm_mfma<64, 128, true, true, f16><<<blocks(N, 64), 256, 0, stream>>>((const f16*)AX16, Wt1, b1, (f16*)H1, N);
        // layer 2: B16 = relu( A_hat (H1 W2) + b2 )
        k_gemm_mfma<128, 128, false, false, f16><<<blocks(N, 64), 256, 0, stream>>>((const f16*)H1, Wt2, nullptr, (f16*)P16a, N);
        k_agg16<128, true, true, __half><<<blocks(N, 16), 256, 0, stream>>>(P16a, starts, csr, dinv, b2, B16, N);
        // layer 3: H3 = A_hat (B16 W3) + b3
        k_gemm_mfma<128, 64, false, false, f16><<<blocks(N, 64), 256, 0, stream>>>((const f16*)B16, Wt3, nullptr, (f16*)P16b, N);
        k_agg16<64, true, false, float><<<blocks(N, 32), 256, 0, stream>>>(P16b, starts, csr, dinv, b3, H3, N);
        // node-parallel pool + per-graph classifier
        k_pool_part<<<blocks(N, 64), 256, 0, stream>>>(H3, batch, N, pooled);
        k_final2<<<Gn, 64, 0, stream>>>(pooled, batch, N, Wl, bl, (float*)d_out, C);
    } else {
        k_gemm_naive<<<blocks((long)N * F1, BLK), BLK, 0, stream>>>(x, W1, Afb, N, K0, F1);
        k_aggregate4<128><<<blocks(N, 8), 256, 0, stream>>>(Afb, starts, csr, dinv, b1, Bfb, N, 1);
        k_gemm_naive<<<blocks((long)N * F2, BLK), BLK, 0, stream>>>(Bfb, W2, Afb, N, F1, F2);
        k_aggregate4<128><<<blocks(N, 8), 256, 0, stream>>>(Afb, starts, csr, dinv, b2, Bfb, N, 1);
        k_gemm_naive<<<blocks((long)N * F3, BLK), BLK, 0, stream>>>(Bfb, W3, Afb, N, F2, F3);
        k_aggregate4<64><<<blocks(N, 16), 256, 0, stream>>>(Afb, starts, csr, dinv, b3, Bfb, N, 0);
        k_pool<<<Gn, F3, 0, stream>>>(Bfb, batch, N, F3, pooled);
        k_final<<<blocks(Gn * C, BLK), BLK, 0, stream>>>(pooled, Wl, bl, (float*)d_out, Gn, F3, C);
    }
}